// Round 1
// baseline (1245.588 us; speedup 1.0000x reference)
//
#include <hip/hip_runtime.h>
#include <hip/hip_bf16.h>
#include <cstdint>
#include <cstddef>

#define EMBED  1024
#define NEXP   8
#define HIDDEN 4096
#define TOKENS 4096
#define KTOT   (NEXP * HIDDEN)   // 32768

typedef __attribute__((ext_vector_type(8))) short bf16x8;
typedef __attribute__((ext_vector_type(4))) float f32x4;
using bf16 = __hip_bfloat16;

// ---------------- async global->LDS (16B per lane) ----------------
__device__ __forceinline__ void gload_lds16(const void* g, void* l) {
    __builtin_amdgcn_global_load_lds((const __attribute__((address_space(1))) void*)g,
                                     (__attribute__((address_space(3))) void*)l,
                                     16, 0, 0);
}

// ---------------- fp32 -> bf16 elementwise convert ----------------
__global__ void cvt_kernel(const float* __restrict__ in, bf16* __restrict__ out, size_t n) {
    size_t i = ((size_t)blockIdx.x * blockDim.x + threadIdx.x) * 4;
    if (i + 3 < n) {
        float4 v = *(const float4*)(in + i);
        out[i + 0] = __float2bfloat16(v.x);
        out[i + 1] = __float2bfloat16(v.y);
        out[i + 2] = __float2bfloat16(v.z);
        out[i + 3] = __float2bfloat16(v.w);
    }
}

// ------------- transpose + convert: out[e][n][k] = in[e][k][n] -------------
// in  : per-expert [K][N] fp32, expert stride in_estride
// out : per-expert base out + e*out_eoff, element [n*ldo + k], bf16
__global__ void transpose_cvt(const float* __restrict__ in, bf16* __restrict__ out,
                              int K, int N, size_t in_estride, size_t out_eoff, int ldo) {
    const int e = blockIdx.z;
    const float* ine = in + (size_t)e * in_estride;
    bf16* oute = out + (size_t)e * out_eoff;
    __shared__ float tile[32][33];
    const int n0 = blockIdx.x * 32, k0 = blockIdx.y * 32;
    const int tx = threadIdx.x, ty = threadIdx.y;
    #pragma unroll
    for (int i = ty; i < 32; i += 8)
        tile[i][tx] = ine[(size_t)(k0 + i) * N + n0 + tx];
    __syncthreads();
    #pragma unroll
    for (int i = ty; i < 32; i += 8)
        oute[(size_t)(n0 + i) * ldo + k0 + tx] = __float2bfloat16(tile[tx][i]);
}

// ---------------- router: per-token top-2 masked softmax ----------------
__global__ void router_kernel(const float* __restrict__ x, const float* __restrict__ Wr,
                              const float* __restrict__ br, float* __restrict__ w) {
    const int t = blockIdx.x;
    const int lane = threadIdx.x;  // 64 threads
    const float* xt = x + (size_t)t * EMBED;
    float s[NEXP];
    #pragma unroll
    for (int e = 0; e < NEXP; e++) s[e] = 0.f;
    for (int k = lane; k < EMBED; k += 64) {
        const float xv = xt[k];
        const float* wrk = Wr + (size_t)k * NEXP;
        #pragma unroll
        for (int e = 0; e < NEXP; e++) s[e] = fmaf(xv, wrk[e], s[e]);
    }
    #pragma unroll
    for (int e = 0; e < NEXP; e++) {
        #pragma unroll
        for (int off = 32; off >= 1; off >>= 1)
            s[e] += __shfl_xor(s[e], off);
    }
    if (lane == 0) {
        float sc[NEXP];
        #pragma unroll
        for (int e = 0; e < NEXP; e++) sc[e] = s[e] + br[e];
        // top-2 (lower index wins ties, matching lax.top_k)
        int i1 = 0; float m1 = sc[0];
        #pragma unroll
        for (int e = 1; e < NEXP; e++) if (sc[e] > m1) { m1 = sc[e]; i1 = e; }
        int i2 = -1; float m2 = -1e30f;
        #pragma unroll
        for (int e = 0; e < NEXP; e++) if (e != i1 && sc[e] > m2) { m2 = sc[e]; i2 = e; }
        const float mx = fmaxf(m1, 0.f);
        const float denom = 6.f * expf(0.f - mx) + expf(m1 - mx) + expf(m2 - mx);
        #pragma unroll
        for (int e = 0; e < NEXP; e++) {
            float v = (e == i1) ? m1 : ((e == i2) ? m2 : 0.f);
            w[(size_t)t * NEXP + e] = expf(v - mx) / denom;
        }
    }
}

// ---------------- GEMM pass 1: h' = w[t,e] * relu(x @ W1_e + b1_e) ----------------
// A  : x_bf16 chunk [M][EMBED], Bt : w1t [NEXP][HIDDEN][EMBED]
// H  : [M][KTOT] bf16, writes columns e*HIDDEN + [bcol..bcol+128)
__global__ __launch_bounds__(256) void gemm1(const bf16* __restrict__ A,
                                             const bf16* __restrict__ Bt,
                                             const float* __restrict__ b1,
                                             const float* __restrict__ rw,
                                             bf16* __restrict__ H) {
    const int e = blockIdx.z;
    const int brow = blockIdx.y * 128;
    const int bcol = blockIdx.x * 128;
    const bf16* Be = Bt + (size_t)e * HIDDEN * EMBED;
    __shared__ __align__(16) bf16 As[128 * 32];
    __shared__ __align__(16) bf16 Bs[128 * 32];
    const int tid = threadIdx.x;
    f32x4 acc[4][4] = {};

    const int seg0 = tid, seg1 = tid + 256;
    const int r0 = seg0 >> 2, c0 = seg0 & 3;
    const int r1 = seg1 >> 2, c1 = seg1 & 3;
    const bf16* ga0 = A + (size_t)(brow + r0) * EMBED + c0 * 8;
    const bf16* ga1 = A + (size_t)(brow + r1) * EMBED + c1 * 8;
    const bf16* gb0 = Be + (size_t)(bcol + r0) * EMBED + c0 * 8;
    const bf16* gb1 = Be + (size_t)(bcol + r1) * EMBED + c1 * 8;

    const int lane = tid & 63, wid = tid >> 6;
    const int wv_r = (wid >> 1) * 64, wv_c = (wid & 1) * 64;
    const int fr = lane & 15, kb = (lane >> 4) * 8;

    for (int kt = 0; kt < EMBED; kt += 32) {
        gload_lds16(ga0 + kt, As + seg0 * 8);
        gload_lds16(ga1 + kt, As + seg1 * 8);
        gload_lds16(gb0 + kt, Bs + seg0 * 8);
        gload_lds16(gb1 + kt, Bs + seg1 * 8);
        __syncthreads();
        bf16x8 af[4], bfr[4];
        #pragma unroll
        for (int m = 0; m < 4; m++) af[m] = *(const bf16x8*)&As[(wv_r + m * 16 + fr) * 32 + kb];
        #pragma unroll
        for (int n = 0; n < 4; n++) bfr[n] = *(const bf16x8*)&Bs[(wv_c + n * 16 + fr) * 32 + kb];
        #pragma unroll
        for (int m = 0; m < 4; m++)
            #pragma unroll
            for (int n = 0; n < 4; n++)
                acc[m][n] = __builtin_amdgcn_mfma_f32_16x16x32_bf16(af[m], bfr[n], acc[m][n], 0, 0, 0);
        __syncthreads();
    }

    #pragma unroll
    for (int n = 0; n < 4; n++) {
        const int col = bcol + wv_c + n * 16 + fr;
        const float bias = b1[e * HIDDEN + col];
        #pragma unroll
        for (int m = 0; m < 4; m++) {
            const int rowb = brow + wv_r + m * 16 + (lane >> 4) * 4;
            #pragma unroll
            for (int j = 0; j < 4; j++) {
                const int row = rowb + j;
                float v = acc[m][n][j] + bias;
                v = fmaxf(v, 0.f) * rw[(size_t)row * NEXP + e];
                H[(size_t)row * KTOT + e * HIDDEN + col] = __float2bfloat16(v);
            }
        }
    }
}

// ---------------- GEMM pass 2: out = h' @ W2_stacked (+ Sum_e w*b2), split-K=4 ----------------
__global__ __launch_bounds__(256) void gemm2(const bf16* __restrict__ A,   // h' [M][KTOT]
                                             const bf16* __restrict__ Bt,  // w2t [EMBED][KTOT]
                                             const float* __restrict__ b2, // [NEXP][EMBED]
                                             const float* __restrict__ rw, // [M][8]
                                             float* __restrict__ out) {    // [M][EMBED]
    const int kc = blockIdx.z;   // 0..3
    const int brow = blockIdx.y * 128;
    const int bcol = blockIdx.x * 128;
    __shared__ __align__(16) bf16 As[128 * 32];
    __shared__ __align__(16) bf16 Bs[128 * 32];
    const int tid = threadIdx.x;
    f32x4 acc[4][4] = {};

    const int seg0 = tid, seg1 = tid + 256;
    const int r0 = seg0 >> 2, c0 = seg0 & 3;
    const int r1 = seg1 >> 2, c1 = seg1 & 3;
    const bf16* ga0 = A + (size_t)(brow + r0) * KTOT + c0 * 8;
    const bf16* ga1 = A + (size_t)(brow + r1) * KTOT + c1 * 8;
    const bf16* gb0 = Bt + (size_t)(bcol + r0) * KTOT + c0 * 8;
    const bf16* gb1 = Bt + (size_t)(bcol + r1) * KTOT + c1 * 8;

    const int lane = tid & 63, wid = tid >> 6;
    const int wv_r = (wid >> 1) * 64, wv_c = (wid & 1) * 64;
    const int fr = lane & 15, kb = (lane >> 4) * 8;

    const int k0 = kc * (KTOT / 4), k1 = k0 + (KTOT / 4);
    for (int kt = k0; kt < k1; kt += 32) {
        gload_lds16(ga0 + kt, As + seg0 * 8);
        gload_lds16(ga1 + kt, As + seg1 * 8);
        gload_lds16(gb0 + kt, Bs + seg0 * 8);
        gload_lds16(gb1 + kt, Bs + seg1 * 8);
        __syncthreads();
        bf16x8 af[4], bfr[4];
        #pragma unroll
        for (int m = 0; m < 4; m++) af[m] = *(const bf16x8*)&As[(wv_r + m * 16 + fr) * 32 + kb];
        #pragma unroll
        for (int n = 0; n < 4; n++) bfr[n] = *(const bf16x8*)&Bs[(wv_c + n * 16 + fr) * 32 + kb];
        #pragma unroll
        for (int m = 0; m < 4; m++)
            #pragma unroll
            for (int n = 0; n < 4; n++)
                acc[m][n] = __builtin_amdgcn_mfma_f32_16x16x32_bf16(af[m], bfr[n], acc[m][n], 0, 0, 0);
        __syncthreads();
    }

    #pragma unroll
    for (int n = 0; n < 4; n++) {
        const int col = bcol + wv_c + n * 16 + fr;
        #pragma unroll
        for (int m = 0; m < 4; m++) {
            const int rowb = brow + wv_r + m * 16 + (lane >> 4) * 4;
            #pragma unroll
            for (int j = 0; j < 4; j++) {
                const int row = rowb + j;
                float v = acc[m][n][j];
                if (kc == 0) {
                    const float* wrow = rw + (size_t)row * NEXP;
                    float s = 0.f;
                    #pragma unroll
                    for (int e = 0; e < NEXP; e++) s = fmaf(wrow[e], b2[e * EMBED + col], s);
                    v += s;
                }
                atomicAdd(out + (size_t)row * EMBED + col, v);
            }
        }
    }
}

extern "C" void kernel_launch(void* const* d_in, const int* in_sizes, int n_in,
                              void* d_out, int out_size, void* d_ws, size_t ws_size,
                              hipStream_t stream) {
    const float* x  = (const float*)d_in[0];
    const float* W1 = (const float*)d_in[1];
    const float* b1 = (const float*)d_in[2];
    const float* W2 = (const float*)d_in[3];
    const float* b2 = (const float*)d_in[4];
    const float* Wr = (const float*)d_in[5];
    const float* br = (const float*)d_in[6];
    float* out = (float*)d_out;

    uint8_t* ws = (uint8_t*)d_ws;
    size_t off = 0;
    auto walloc = [&](size_t bytes) -> void* {
        void* p = ws + off;
        off += (bytes + 255) & ~(size_t)255;
        return p;
    };
    float* rw  = (float*)walloc((size_t)TOKENS * NEXP * 4);
    bf16* xb   = (bf16*)walloc((size_t)TOKENS * EMBED * 2);
    bf16* w1t  = (bf16*)walloc((size_t)NEXP * HIDDEN * EMBED * 2);
    bf16* w2t  = (bf16*)walloc((size_t)EMBED * KTOT * 2);
    size_t remain = (ws_size > off) ? (ws_size - off) : 0;
    long long mc = (long long)(remain / ((size_t)KTOT * 2)) / 128 * 128;
    if (mc > TOKENS) mc = TOKENS;
    if (mc < 128) mc = 128;  // minimum viable; ws presumed large enough
    const int Mc = (int)mc;
    bf16* hbuf = (bf16*)walloc((size_t)Mc * KTOT * 2);

    hipMemsetAsync(d_out, 0, (size_t)out_size * sizeof(float), stream);

    cvt_kernel<<<4096, 256, 0, stream>>>(x, xb, (size_t)TOKENS * EMBED);

    dim3 tb(32, 8);
    // W1 [e][d][h] -> w1t [e][h][d]
    transpose_cvt<<<dim3(HIDDEN / 32, EMBED / 32, NEXP), tb, 0, stream>>>(
        W1, w1t, EMBED, HIDDEN, (size_t)EMBED * HIDDEN, (size_t)HIDDEN * EMBED, EMBED);
    // W2 [e][h][n] -> w2t [n][e*HIDDEN + h]
    transpose_cvt<<<dim3(EMBED / 32, HIDDEN / 32, NEXP), tb, 0, stream>>>(
        W2, w2t, HIDDEN, EMBED, (size_t)HIDDEN * EMBED, (size_t)HIDDEN, KTOT);

    router_kernel<<<TOKENS, 64, 0, stream>>>(x, Wr, br, rw);

    for (int m0 = 0; m0 < TOKENS; m0 += Mc) {
        const int M = (TOKENS - m0 < Mc) ? (TOKENS - m0) : Mc;
        gemm1<<<dim3(HIDDEN / 128, M / 128, NEXP), 256, 0, stream>>>(
            xb + (size_t)m0 * EMBED, w1t, b1, rw + (size_t)m0 * NEXP, hbuf);
        gemm2<<<dim3(EMBED / 128, M / 128, 4), 256, 0, stream>>>(
            hbuf, w2t, b2, rw + (size_t)m0 * NEXP, out + (size_t)m0 * EMBED);
    }
}

// Round 2
// 1186.773 us; speedup vs baseline: 1.0496x; 1.0496x over previous
//
#include <hip/hip_runtime.h>
#include <hip/hip_bf16.h>
#include <cstdint>
#include <cstddef>

#define EMBED  1024
#define NEXP   8
#define HIDDEN 4096
#define TOKENS 4096
#define KTOT   (NEXP * HIDDEN)   // 32768
#define KSPLIT 16
#define KCHUNK (KTOT / KSPLIT)   // 2048
#define MCHUNK 1024              // token chunk: h' chunk = 64 MB, fits L3 with w2t

typedef __attribute__((ext_vector_type(8))) short bf16x8;
typedef __attribute__((ext_vector_type(4))) float f32x4;
using bf16 = __hip_bfloat16;

// ---------------- async global->LDS (16B per lane) ----------------
__device__ __forceinline__ void gload_lds16(const void* g, void* l) {
    __builtin_amdgcn_global_load_lds((const __attribute__((address_space(1))) void*)g,
                                     (__attribute__((address_space(3))) void*)l,
                                     16, 0, 0);
}

// ---------------- fp32 -> bf16 elementwise convert ----------------
__global__ void cvt_kernel(const float* __restrict__ in, bf16* __restrict__ out, size_t n) {
    size_t i = ((size_t)blockIdx.x * blockDim.x + threadIdx.x) * 4;
    if (i + 3 < n) {
        float4 v = *(const float4*)(in + i);
        out[i + 0] = __float2bfloat16(v.x);
        out[i + 1] = __float2bfloat16(v.y);
        out[i + 2] = __float2bfloat16(v.z);
        out[i + 3] = __float2bfloat16(v.w);
    }
}

// ------------- transpose + convert: out[e][n][k] = in[e][k][n] -------------
__global__ void transpose_cvt(const float* __restrict__ in, bf16* __restrict__ out,
                              int K, int N, size_t in_estride, size_t out_eoff, int ldo) {
    const int e = blockIdx.z;
    const float* ine = in + (size_t)e * in_estride;
    bf16* oute = out + (size_t)e * out_eoff;
    __shared__ float tile[32][33];
    const int n0 = blockIdx.x * 32, k0 = blockIdx.y * 32;
    const int tx = threadIdx.x, ty = threadIdx.y;
    #pragma unroll
    for (int i = ty; i < 32; i += 8)
        tile[i][tx] = ine[(size_t)(k0 + i) * N + n0 + tx];
    __syncthreads();
    #pragma unroll
    for (int i = ty; i < 32; i += 8)
        oute[(size_t)(n0 + i) * ldo + k0 + tx] = __float2bfloat16(tile[tx][i]);
}

// ---------------- router: per-token top-2 masked softmax ----------------
__global__ void router_kernel(const float* __restrict__ x, const float* __restrict__ Wr,
                              const float* __restrict__ br, float* __restrict__ w) {
    const int t = blockIdx.x;
    const int lane = threadIdx.x;  // 64 threads
    const float* xt = x + (size_t)t * EMBED;
    float s[NEXP];
    #pragma unroll
    for (int e = 0; e < NEXP; e++) s[e] = 0.f;
    for (int k = lane; k < EMBED; k += 64) {
        const float xv = xt[k];
        const float* wrk = Wr + (size_t)k * NEXP;
        #pragma unroll
        for (int e = 0; e < NEXP; e++) s[e] = fmaf(xv, wrk[e], s[e]);
    }
    #pragma unroll
    for (int e = 0; e < NEXP; e++) {
        #pragma unroll
        for (int off = 32; off >= 1; off >>= 1)
            s[e] += __shfl_xor(s[e], off);
    }
    if (lane == 0) {
        float sc[NEXP];
        #pragma unroll
        for (int e = 0; e < NEXP; e++) sc[e] = s[e] + br[e];
        int i1 = 0; float m1 = sc[0];
        #pragma unroll
        for (int e = 1; e < NEXP; e++) if (sc[e] > m1) { m1 = sc[e]; i1 = e; }
        int i2 = -1; float m2 = -1e30f;
        #pragma unroll
        for (int e = 0; e < NEXP; e++) if (e != i1 && sc[e] > m2) { m2 = sc[e]; i2 = e; }
        const float mx = fmaxf(m1, 0.f);
        const float denom = 6.f * expf(0.f - mx) + expf(m1 - mx) + expf(m2 - mx);
        #pragma unroll
        for (int e = 0; e < NEXP; e++) {
            float v = (e == i1) ? m1 : ((e == i2) ? m2 : 0.f);
            w[(size_t)t * NEXP + e] = expf(v - mx) / denom;
        }
    }
}

// ---------------- GEMM pass 1: h' = w[t,e] * relu(x @ W1_e + b1_e) ----------------
__global__ __launch_bounds__(256) void gemm1(const bf16* __restrict__ A,
                                             const bf16* __restrict__ Bt,
                                             const float* __restrict__ b1,
                                             const float* __restrict__ rw,
                                             bf16* __restrict__ H) {
    const int e = blockIdx.z;
    const int brow = blockIdx.y * 128;
    const int bcol = blockIdx.x * 128;
    const bf16* Be = Bt + (size_t)e * HIDDEN * EMBED;
    __shared__ __align__(16) bf16 As[128 * 32];
    __shared__ __align__(16) bf16 Bs[128 * 32];
    const int tid = threadIdx.x;
    f32x4 acc[4][4] = {};

    const int seg0 = tid, seg1 = tid + 256;
    const int r0 = seg0 >> 2, c0 = seg0 & 3;
    const int r1 = seg1 >> 2, c1 = seg1 & 3;
    const bf16* ga0 = A + (size_t)(brow + r0) * EMBED + c0 * 8;
    const bf16* ga1 = A + (size_t)(brow + r1) * EMBED + c1 * 8;
    const bf16* gb0 = Be + (size_t)(bcol + r0) * EMBED + c0 * 8;
    const bf16* gb1 = Be + (size_t)(bcol + r1) * EMBED + c1 * 8;

    const int lane = tid & 63, wid = tid >> 6;
    const int wv_r = (wid >> 1) * 64, wv_c = (wid & 1) * 64;
    const int fr = lane & 15, kb = (lane >> 4) * 8;

    for (int kt = 0; kt < EMBED; kt += 32) {
        gload_lds16(ga0 + kt, As + seg0 * 8);
        gload_lds16(ga1 + kt, As + seg1 * 8);
        gload_lds16(gb0 + kt, Bs + seg0 * 8);
        gload_lds16(gb1 + kt, Bs + seg1 * 8);
        __syncthreads();
        bf16x8 af[4], bfr[4];
        #pragma unroll
        for (int m = 0; m < 4; m++) af[m] = *(const bf16x8*)&As[(wv_r + m * 16 + fr) * 32 + kb];
        #pragma unroll
        for (int n = 0; n < 4; n++) bfr[n] = *(const bf16x8*)&Bs[(wv_c + n * 16 + fr) * 32 + kb];
        #pragma unroll
        for (int m = 0; m < 4; m++)
            #pragma unroll
            for (int n = 0; n < 4; n++)
                acc[m][n] = __builtin_amdgcn_mfma_f32_16x16x32_bf16(af[m], bfr[n], acc[m][n], 0, 0, 0);
        __syncthreads();
    }

    #pragma unroll
    for (int n = 0; n < 4; n++) {
        const int col = bcol + wv_c + n * 16 + fr;
        const float bias = b1[e * HIDDEN + col];
        #pragma unroll
        for (int m = 0; m < 4; m++) {
            const int rowb = brow + wv_r + m * 16 + (lane >> 4) * 4;
            #pragma unroll
            for (int j = 0; j < 4; j++) {
                const int row = rowb + j;
                float v = acc[m][n][j] + bias;
                v = fmaxf(v, 0.f) * rw[(size_t)row * NEXP + e];
                H[(size_t)row * KTOT + e * HIDDEN + col] = __float2bfloat16(v);
            }
        }
    }
}

// ---------------- GEMM pass 2: out = h' @ W2_stacked (+ Sum_e w*b2), split-K=16 ----------------
__global__ __launch_bounds__(256) void gemm2(const bf16* __restrict__ A,   // h' [M][KTOT]
                                             const bf16* __restrict__ Bt,  // w2t [EMBED][KTOT]
                                             const float* __restrict__ b2, // [NEXP][EMBED]
                                             const float* __restrict__ rw, // [M][8]
                                             float* __restrict__ out) {    // [M][EMBED]
    const int kc = blockIdx.z;   // 0..KSPLIT-1
    const int brow = blockIdx.y * 128;
    const int bcol = blockIdx.x * 128;
    __shared__ __align__(16) bf16 As[128 * 32];
    __shared__ __align__(16) bf16 Bs[128 * 32];
    const int tid = threadIdx.x;
    f32x4 acc[4][4] = {};

    const int seg0 = tid, seg1 = tid + 256;
    const int r0 = seg0 >> 2, c0 = seg0 & 3;
    const int r1 = seg1 >> 2, c1 = seg1 & 3;
    const bf16* ga0 = A + (size_t)(brow + r0) * KTOT + c0 * 8;
    const bf16* ga1 = A + (size_t)(brow + r1) * KTOT + c1 * 8;
    const bf16* gb0 = Bt + (size_t)(bcol + r0) * KTOT + c0 * 8;
    const bf16* gb1 = Bt + (size_t)(bcol + r1) * KTOT + c1 * 8;

    const int lane = tid & 63, wid = tid >> 6;
    const int wv_r = (wid >> 1) * 64, wv_c = (wid & 1) * 64;
    const int fr = lane & 15, kb = (lane >> 4) * 8;

    const int k0 = kc * KCHUNK, k1 = k0 + KCHUNK;
    for (int kt = k0; kt < k1; kt += 32) {
        gload_lds16(ga0 + kt, As + seg0 * 8);
        gload_lds16(ga1 + kt, As + seg1 * 8);
        gload_lds16(gb0 + kt, Bs + seg0 * 8);
        gload_lds16(gb1 + kt, Bs + seg1 * 8);
        __syncthreads();
        bf16x8 af[4], bfr[4];
        #pragma unroll
        for (int m = 0; m < 4; m++) af[m] = *(const bf16x8*)&As[(wv_r + m * 16 + fr) * 32 + kb];
        #pragma unroll
        for (int n = 0; n < 4; n++) bfr[n] = *(const bf16x8*)&Bs[(wv_c + n * 16 + fr) * 32 + kb];
        #pragma unroll
        for (int m = 0; m < 4; m++)
            #pragma unroll
            for (int n = 0; n < 4; n++)
                acc[m][n] = __builtin_amdgcn_mfma_f32_16x16x32_bf16(af[m], bfr[n], acc[m][n], 0, 0, 0);
        __syncthreads();
    }

    #pragma unroll
    for (int n = 0; n < 4; n++) {
        const int col = bcol + wv_c + n * 16 + fr;
        #pragma unroll
        for (int m = 0; m < 4; m++) {
            const int rowb = brow + wv_r + m * 16 + (lane >> 4) * 4;
            #pragma unroll
            for (int j = 0; j < 4; j++) {
                const int row = rowb + j;
                float v = acc[m][n][j];
                if (kc == 0) {
                    const float* wrow = rw + (size_t)row * NEXP;
                    float s = 0.f;
                    #pragma unroll
                    for (int e = 0; e < NEXP; e++) s = fmaf(wrow[e], b2[e * EMBED + col], s);
                    v += s;
                }
                atomicAdd(out + (size_t)row * EMBED + col, v);
            }
        }
    }
}

extern "C" void kernel_launch(void* const* d_in, const int* in_sizes, int n_in,
                              void* d_out, int out_size, void* d_ws, size_t ws_size,
                              hipStream_t stream) {
    const float* x  = (const float*)d_in[0];
    const float* W1 = (const float*)d_in[1];
    const float* b1 = (const float*)d_in[2];
    const float* W2 = (const float*)d_in[3];
    const float* b2 = (const float*)d_in[4];
    const float* Wr = (const float*)d_in[5];
    const float* br = (const float*)d_in[6];
    float* out = (float*)d_out;

    uint8_t* ws = (uint8_t*)d_ws;
    size_t off = 0;
    auto walloc = [&](size_t bytes) -> void* {
        void* p = ws + off;
        off += (bytes + 255) & ~(size_t)255;
        return p;
    };
    float* rw  = (float*)walloc((size_t)TOKENS * NEXP * 4);
    bf16* xb   = (bf16*)walloc((size_t)TOKENS * EMBED * 2);
    bf16* w1t  = (bf16*)walloc((size_t)NEXP * HIDDEN * EMBED * 2);
    bf16* w2t  = (bf16*)walloc((size_t)EMBED * KTOT * 2);
    size_t remain = (ws_size > off) ? (ws_size - off) : 0;
    long long mc = (long long)(remain / ((size_t)KTOT * 2)) / 128 * 128;
    if (mc > MCHUNK) mc = MCHUNK;  // cap: keep h' chunk <= 64 MB for L3 residency
    if (mc < 128) mc = 128;
    const int Mc = (int)mc;
    bf16* hbuf = (bf16*)walloc((size_t)Mc * KTOT * 2);

    hipMemsetAsync(d_out, 0, (size_t)out_size * sizeof(float), stream);

    cvt_kernel<<<4096, 256, 0, stream>>>(x, xb, (size_t)TOKENS * EMBED);

    dim3 tb(32, 8);
    // W1 [e][d][h] -> w1t [e][h][d]
    transpose_cvt<<<dim3(HIDDEN / 32, EMBED / 32, NEXP), tb, 0, stream>>>(
        W1, w1t, EMBED, HIDDEN, (size_t)EMBED * HIDDEN, (size_t)HIDDEN * EMBED, EMBED);
    // W2 [e][h][n] -> w2t [n][e*HIDDEN + h]
    transpose_cvt<<<dim3(EMBED / 32, HIDDEN / 32, NEXP), tb, 0, stream>>>(
        W2, w2t, HIDDEN, EMBED, (size_t)HIDDEN * EMBED, (size_t)HIDDEN, KTOT);

    router_kernel<<<TOKENS, 64, 0, stream>>>(x, Wr, br, rw);

    for (int m0 = 0; m0 < TOKENS; m0 += Mc) {
        const int M = (TOKENS - m0 < Mc) ? (TOKENS - m0) : Mc;
        gemm1<<<dim3(HIDDEN / 128, M / 128, NEXP), 256, 0, stream>>>(
            xb + (size_t)m0 * EMBED, w1t, b1, rw + (size_t)m0 * NEXP, hbuf);
        gemm2<<<dim3(EMBED / 128, M / 128, KSPLIT), 256, 0, stream>>>(
            hbuf, w2t, b2, rw + (size_t)m0 * NEXP, out + (size_t)m0 * EMBED);
    }
}

// Round 3
// 1178.346 us; speedup vs baseline: 1.0571x; 1.0072x over previous
//
#include <hip/hip_runtime.h>
#include <hip/hip_bf16.h>
#include <cstdint>
#include <cstddef>

#define EMBED  1024
#define NEXP   8
#define HIDDEN 4096
#define TOKENS 4096
#define KTOT   (NEXP * HIDDEN)   // 32768
#define KSPLIT 16                // 2 K-slabs per expert
#define KCHUNK 2048
#define MCHUNK 1024              // token chunk: h' chunk = 64 MB, fits L3 with w2t

typedef __attribute__((ext_vector_type(8))) short bf16x8;
typedef __attribute__((ext_vector_type(4))) float f32x4;
using bf16 = __hip_bfloat16;

// ---------------- async global->LDS (16B per lane) ----------------
__device__ __forceinline__ void gload_lds16(const void* g, void* l) {
    __builtin_amdgcn_global_load_lds((const __attribute__((address_space(1))) void*)g,
                                     (__attribute__((address_space(3))) void*)l,
                                     16, 0, 0);
}

// ---------------- fp32 -> bf16 elementwise convert ----------------
__global__ void cvt_kernel(const float* __restrict__ in, bf16* __restrict__ out, size_t n) {
    size_t i = ((size_t)blockIdx.x * blockDim.x + threadIdx.x) * 4;
    if (i + 3 < n) {
        float4 v = *(const float4*)(in + i);
        out[i + 0] = __float2bfloat16(v.x);
        out[i + 1] = __float2bfloat16(v.y);
        out[i + 2] = __float2bfloat16(v.z);
        out[i + 3] = __float2bfloat16(v.w);
    }
}

// ------------- transpose + convert: out[e][n][k] = in[e][k][n] -------------
__global__ void transpose_cvt(const float* __restrict__ in, bf16* __restrict__ out,
                              int K, int N, size_t in_estride, size_t out_eoff, int ldo) {
    const int e = blockIdx.z;
    const float* ine = in + (size_t)e * in_estride;
    bf16* oute = out + (size_t)e * out_eoff;
    __shared__ float tile[32][33];
    const int n0 = blockIdx.x * 32, k0 = blockIdx.y * 32;
    const int tx = threadIdx.x, ty = threadIdx.y;
    #pragma unroll
    for (int i = ty; i < 32; i += 8)
        tile[i][tx] = ine[(size_t)(k0 + i) * N + n0 + tx];
    __syncthreads();
    #pragma unroll
    for (int i = ty; i < 32; i += 8)
        oute[(size_t)(n0 + i) * ldo + k0 + tx] = __float2bfloat16(tile[tx][i]);
}

// ---------------- router: per-token top-2 masked softmax ----------------
__global__ void router_kernel(const float* __restrict__ x, const float* __restrict__ Wr,
                              const float* __restrict__ br, float* __restrict__ w) {
    const int t = blockIdx.x;
    const int lane = threadIdx.x;  // 64 threads
    const float* xt = x + (size_t)t * EMBED;
    float s[NEXP];
    #pragma unroll
    for (int e = 0; e < NEXP; e++) s[e] = 0.f;
    for (int k = lane; k < EMBED; k += 64) {
        const float xv = xt[k];
        const float* wrk = Wr + (size_t)k * NEXP;
        #pragma unroll
        for (int e = 0; e < NEXP; e++) s[e] = fmaf(xv, wrk[e], s[e]);
    }
    #pragma unroll
    for (int e = 0; e < NEXP; e++) {
        #pragma unroll
        for (int off = 32; off >= 1; off >>= 1)
            s[e] += __shfl_xor(s[e], off);
    }
    if (lane == 0) {
        float sc[NEXP];
        #pragma unroll
        for (int e = 0; e < NEXP; e++) sc[e] = s[e] + br[e];
        int i1 = 0; float m1 = sc[0];
        #pragma unroll
        for (int e = 1; e < NEXP; e++) if (sc[e] > m1) { m1 = sc[e]; i1 = e; }
        int i2 = -1; float m2 = -1e30f;
        #pragma unroll
        for (int e = 0; e < NEXP; e++) if (e != i1 && sc[e] > m2) { m2 = sc[e]; i2 = e; }
        const float mx = fmaxf(m1, 0.f);
        const float denom = 6.f * expf(0.f - mx) + expf(m1 - mx) + expf(m2 - mx);
        #pragma unroll
        for (int e = 0; e < NEXP; e++) {
            float v = (e == i1) ? m1 : ((e == i2) ? m2 : 0.f);
            w[(size_t)t * NEXP + e] = expf(v - mx) / denom;
        }
    }
}

// ---------------- GEMM pass 1: h'[e][row][col] = w[t,e] * relu(x @ W1_e + b1_e) ----------------
__global__ __launch_bounds__(256) void gemm1(const bf16* __restrict__ A,
                                             const bf16* __restrict__ Bt,
                                             const float* __restrict__ b1,
                                             const float* __restrict__ rw,
                                             bf16* __restrict__ H, int eM) {
    const int e = blockIdx.z;
    const int brow = blockIdx.y * 128;
    const int bcol = blockIdx.x * 128;
    const bf16* Be = Bt + (size_t)e * HIDDEN * EMBED;
    bf16* He = H + (size_t)e * eM * HIDDEN;
    __shared__ __align__(16) bf16 As[128 * 32];
    __shared__ __align__(16) bf16 Bs[128 * 32];
    const int tid = threadIdx.x;
    f32x4 acc[4][4] = {};

    const int seg0 = tid, seg1 = tid + 256;
    const int r0 = seg0 >> 2, c0 = seg0 & 3;
    const int r1 = seg1 >> 2, c1 = seg1 & 3;
    const bf16* ga0 = A + (size_t)(brow + r0) * EMBED + c0 * 8;
    const bf16* ga1 = A + (size_t)(brow + r1) * EMBED + c1 * 8;
    const bf16* gb0 = Be + (size_t)(bcol + r0) * EMBED + c0 * 8;
    const bf16* gb1 = Be + (size_t)(bcol + r1) * EMBED + c1 * 8;

    const int lane = tid & 63, wid = tid >> 6;
    const int wv_r = (wid >> 1) * 64, wv_c = (wid & 1) * 64;
    const int fr = lane & 15, kb = (lane >> 4) * 8;

    for (int kt = 0; kt < EMBED; kt += 32) {
        gload_lds16(ga0 + kt, As + seg0 * 8);
        gload_lds16(ga1 + kt, As + seg1 * 8);
        gload_lds16(gb0 + kt, Bs + seg0 * 8);
        gload_lds16(gb1 + kt, Bs + seg1 * 8);
        __syncthreads();
        bf16x8 af[4], bfr[4];
        #pragma unroll
        for (int m = 0; m < 4; m++) af[m] = *(const bf16x8*)&As[(wv_r + m * 16 + fr) * 32 + kb];
        #pragma unroll
        for (int n = 0; n < 4; n++) bfr[n] = *(const bf16x8*)&Bs[(wv_c + n * 16 + fr) * 32 + kb];
        #pragma unroll
        for (int m = 0; m < 4; m++)
            #pragma unroll
            for (int n = 0; n < 4; n++)
                acc[m][n] = __builtin_amdgcn_mfma_f32_16x16x32_bf16(af[m], bfr[n], acc[m][n], 0, 0, 0);
        __syncthreads();
    }

    #pragma unroll
    for (int n = 0; n < 4; n++) {
        const int col = bcol + wv_c + n * 16 + fr;
        const float bias = b1[e * HIDDEN + col];
        #pragma unroll
        for (int m = 0; m < 4; m++) {
            const int rowb = brow + wv_r + m * 16 + (lane >> 4) * 4;
            #pragma unroll
            for (int j = 0; j < 4; j++) {
                const int row = rowb + j;
                float v = acc[m][n][j] + bias;
                v = fmaxf(v, 0.f) * rw[(size_t)row * NEXP + e];
                He[(size_t)row * HIDDEN + col] = __float2bfloat16(v);
            }
        }
    }
}

// ------- GEMM pass 2: out = Sum_e h'_e @ W2_e (+ Sum_e w*b2), split per (expert, K-half) -------
__global__ __launch_bounds__(256) void gemm2(const bf16* __restrict__ A,   // h' [NEXP][eM][HIDDEN]
                                             const bf16* __restrict__ Bt,  // w2t [NEXP][EMBED][HIDDEN]
                                             const float* __restrict__ b2, // [NEXP][EMBED]
                                             const float* __restrict__ rw, // [M][8]
                                             float* __restrict__ out, int eM) { // [M][EMBED]
    const int kc = blockIdx.z;        // 0..15
    const int e  = kc >> 1;           // expert
    const int ks = kc & 1;            // K-half within expert
    const int brow = blockIdx.y * 128;
    const int bcol = blockIdx.x * 128;
    const bf16* Ae = A + (size_t)e * eM * HIDDEN;
    const bf16* Be = Bt + (size_t)e * EMBED * HIDDEN;
    __shared__ __align__(16) bf16 As[128 * 32];
    __shared__ __align__(16) bf16 Bs[128 * 32];
    const int tid = threadIdx.x;
    f32x4 acc[4][4] = {};

    const int seg0 = tid, seg1 = tid + 256;
    const int r0 = seg0 >> 2, c0 = seg0 & 3;
    const int r1 = seg1 >> 2, c1 = seg1 & 3;
    const bf16* ga0 = Ae + (size_t)(brow + r0) * HIDDEN + c0 * 8;
    const bf16* ga1 = Ae + (size_t)(brow + r1) * HIDDEN + c1 * 8;
    const bf16* gb0 = Be + (size_t)(bcol + r0) * HIDDEN + c0 * 8;
    const bf16* gb1 = Be + (size_t)(bcol + r1) * HIDDEN + c1 * 8;

    const int lane = tid & 63, wid = tid >> 6;
    const int wv_r = (wid >> 1) * 64, wv_c = (wid & 1) * 64;
    const int fr = lane & 15, kb = (lane >> 4) * 8;

    const int k0 = ks * KCHUNK, k1 = k0 + KCHUNK;
    for (int kt = k0; kt < k1; kt += 32) {
        gload_lds16(ga0 + kt, As + seg0 * 8);
        gload_lds16(ga1 + kt, As + seg1 * 8);
        gload_lds16(gb0 + kt, Bs + seg0 * 8);
        gload_lds16(gb1 + kt, Bs + seg1 * 8);
        __syncthreads();
        bf16x8 af[4], bfr[4];
        #pragma unroll
        for (int m = 0; m < 4; m++) af[m] = *(const bf16x8*)&As[(wv_r + m * 16 + fr) * 32 + kb];
        #pragma unroll
        for (int n = 0; n < 4; n++) bfr[n] = *(const bf16x8*)&Bs[(wv_c + n * 16 + fr) * 32 + kb];
        #pragma unroll
        for (int m = 0; m < 4; m++)
            #pragma unroll
            for (int n = 0; n < 4; n++)
                acc[m][n] = __builtin_amdgcn_mfma_f32_16x16x32_bf16(af[m], bfr[n], acc[m][n], 0, 0, 0);
        __syncthreads();
    }

    #pragma unroll
    for (int n = 0; n < 4; n++) {
        const int col = bcol + wv_c + n * 16 + fr;
        #pragma unroll
        for (int m = 0; m < 4; m++) {
            const int rowb = brow + wv_r + m * 16 + (lane >> 4) * 4;
            #pragma unroll
            for (int j = 0; j < 4; j++) {
                const int row = rowb + j;
                float v = acc[m][n][j];
                if (kc == 0) {
                    const float* wrow = rw + (size_t)row * NEXP;
                    float s = 0.f;
                    #pragma unroll
                    for (int ee = 0; ee < NEXP; ee++) s = fmaf(wrow[ee], b2[ee * EMBED + col], s);
                    v += s;
                }
                atomicAdd(out + (size_t)row * EMBED + col, v);
            }
        }
    }
}

extern "C" void kernel_launch(void* const* d_in, const int* in_sizes, int n_in,
                              void* d_out, int out_size, void* d_ws, size_t ws_size,
                              hipStream_t stream) {
    const float* x  = (const float*)d_in[0];
    const float* W1 = (const float*)d_in[1];
    const float* b1 = (const float*)d_in[2];
    const float* W2 = (const float*)d_in[3];
    const float* b2 = (const float*)d_in[4];
    const float* Wr = (const float*)d_in[5];
    const float* br = (const float*)d_in[6];
    float* out = (float*)d_out;

    uint8_t* ws = (uint8_t*)d_ws;
    size_t off = 0;
    auto walloc = [&](size_t bytes) -> void* {
        void* p = ws + off;
        off += (bytes + 255) & ~(size_t)255;
        return p;
    };
    float* rw  = (float*)walloc((size_t)TOKENS * NEXP * 4);
    bf16* xb   = (bf16*)walloc((size_t)TOKENS * EMBED * 2);
    bf16* w1t  = (bf16*)walloc((size_t)NEXP * HIDDEN * EMBED * 2);
    bf16* w2t  = (bf16*)walloc((size_t)NEXP * EMBED * HIDDEN * 2);
    size_t remain = (ws_size > off) ? (ws_size - off) : 0;
    long long mc = (long long)(remain / ((size_t)KTOT * 2)) / 128 * 128;
    if (mc > MCHUNK) mc = MCHUNK;  // cap: keep h' chunk <= 64 MB for L3 residency
    if (mc < 128) mc = 128;
    const int Mc = (int)mc;
    bf16* hbuf = (bf16*)walloc((size_t)NEXP * Mc * HIDDEN * 2);

    hipMemsetAsync(d_out, 0, (size_t)out_size * sizeof(float), stream);

    cvt_kernel<<<4096, 256, 0, stream>>>(x, xb, (size_t)TOKENS * EMBED);

    dim3 tb(32, 8);
    // W1 [e][d][h] -> w1t [e][h][d]
    transpose_cvt<<<dim3(HIDDEN / 32, EMBED / 32, NEXP), tb, 0, stream>>>(
        W1, w1t, EMBED, HIDDEN, (size_t)EMBED * HIDDEN, (size_t)HIDDEN * EMBED, EMBED);
    // W2 [e][h][n] -> w2t [e][n][h]
    transpose_cvt<<<dim3(EMBED / 32, HIDDEN / 32, NEXP), tb, 0, stream>>>(
        W2, w2t, HIDDEN, EMBED, (size_t)HIDDEN * EMBED, (size_t)EMBED * HIDDEN, HIDDEN);

    router_kernel<<<TOKENS, 64, 0, stream>>>(x, Wr, br, rw);

    for (int m0 = 0; m0 < TOKENS; m0 += Mc) {
        const int M = (TOKENS - m0 < Mc) ? (TOKENS - m0) : Mc;
        gemm1<<<dim3(HIDDEN / 128, M / 128, NEXP), 256, 0, stream>>>(
            xb + (size_t)m0 * EMBED, w1t, b1, rw + (size_t)m0 * NEXP, hbuf, Mc);
        gemm2<<<dim3(EMBED / 128, M / 128, KSPLIT), 256, 0, stream>>>(
            hbuf, w2t, b2, rw + (size_t)m0 * NEXP, out + (size_t)m0 * EMBED, Mc);
    }
}

// Round 4
// 1149.187 us; speedup vs baseline: 1.0839x; 1.0254x over previous
//
#include <hip/hip_runtime.h>
#include <hip/hip_bf16.h>
#include <cstdint>
#include <cstddef>

#define EMBED  1024
#define NEXP   8
#define HIDDEN 4096
#define TOKENS 4096
#define KTOT   (NEXP * HIDDEN)   // 32768

typedef __attribute__((ext_vector_type(8))) short bf16x8;
typedef __attribute__((ext_vector_type(4))) float f32x4;
using bf16 = __hip_bfloat16;

// ---------------- async global->LDS (16B per lane) ----------------
__device__ __forceinline__ void gload_lds16(const void* g, void* l) {
    __builtin_amdgcn_global_load_lds((const __attribute__((address_space(1))) void*)g,
                                     (__attribute__((address_space(3))) void*)l,
                                     16, 0, 0);
}

// ---------------- fp32 -> bf16 elementwise convert ----------------
__global__ void cvt_kernel(const float* __restrict__ in, bf16* __restrict__ out, size_t n) {
    size_t i = ((size_t)blockIdx.x * blockDim.x + threadIdx.x) * 4;
    if (i + 3 < n) {
        float4 v = *(const float4*)(in + i);
        out[i + 0] = __float2bfloat16(v.x);
        out[i + 1] = __float2bfloat16(v.y);
        out[i + 2] = __float2bfloat16(v.z);
        out[i + 3] = __float2bfloat16(v.w);
    }
}

// ------------- transpose + convert: out[e][n][k] = in[e][k][n] -------------
__global__ void transpose_cvt(const float* __restrict__ in, bf16* __restrict__ out,
                              int K, int N, size_t in_estride, size_t out_eoff, int ldo) {
    const int e = blockIdx.z;
    const float* ine = in + (size_t)e * in_estride;
    bf16* oute = out + (size_t)e * out_eoff;
    __shared__ float tile[32][33];
    const int n0 = blockIdx.x * 32, k0 = blockIdx.y * 32;
    const int tx = threadIdx.x, ty = threadIdx.y;
    #pragma unroll
    for (int i = ty; i < 32; i += 8)
        tile[i][tx] = ine[(size_t)(k0 + i) * N + n0 + tx];
    __syncthreads();
    #pragma unroll
    for (int i = ty; i < 32; i += 8)
        oute[(size_t)(n0 + i) * ldo + k0 + tx] = __float2bfloat16(tile[tx][i]);
}

// ---------------- router: per-token top-2 masked softmax ----------------
__global__ void router_kernel(const float* __restrict__ x, const float* __restrict__ Wr,
                              const float* __restrict__ br, float* __restrict__ w) {
    const int t = blockIdx.x;
    const int lane = threadIdx.x;  // 64 threads
    const float* xt = x + (size_t)t * EMBED;
    float s[NEXP];
    #pragma unroll
    for (int e = 0; e < NEXP; e++) s[e] = 0.f;
    for (int k = lane; k < EMBED; k += 64) {
        const float xv = xt[k];
        const float* wrk = Wr + (size_t)k * NEXP;
        #pragma unroll
        for (int e = 0; e < NEXP; e++) s[e] = fmaf(xv, wrk[e], s[e]);
    }
    #pragma unroll
    for (int e = 0; e < NEXP; e++) {
        #pragma unroll
        for (int off = 32; off >= 1; off >>= 1)
            s[e] += __shfl_xor(s[e], off);
    }
    if (lane == 0) {
        float sc[NEXP];
        #pragma unroll
        for (int e = 0; e < NEXP; e++) sc[e] = s[e] + br[e];
        int i1 = 0; float m1 = sc[0];
        #pragma unroll
        for (int e = 1; e < NEXP; e++) if (sc[e] > m1) { m1 = sc[e]; i1 = e; }
        int i2 = -1; float m2 = -1e30f;
        #pragma unroll
        for (int e = 0; e < NEXP; e++) if (e != i1 && sc[e] > m2) { m2 = sc[e]; i2 = e; }
        const float mx = fmaxf(m1, 0.f);
        const float denom = 6.f * expf(0.f - mx) + expf(m1 - mx) + expf(m2 - mx);
        #pragma unroll
        for (int e = 0; e < NEXP; e++) {
            float v = (e == i1) ? m1 : ((e == i2) ? m2 : 0.f);
            w[(size_t)t * NEXP + e] = expf(v - mx) / denom;
        }
    }
}

// ---- GEMM pass 1 (2-phase dbuf): h'[e][row][col] = w[t,e] * relu(x @ W1_e + b1_e) ----
__global__ __launch_bounds__(256) void gemm1(const bf16* __restrict__ A,   // x [4096][EMBED]
                                             const bf16* __restrict__ Bt,  // w1t [e][HIDDEN][EMBED]
                                             const float* __restrict__ b1,
                                             const float* __restrict__ rw,
                                             bf16* __restrict__ H) {
    const int e = blockIdx.z;
    const int brow = blockIdx.y * 128;
    const int bcol = blockIdx.x * 128;
    const bf16* Be = Bt + (size_t)e * HIDDEN * EMBED;
    bf16* He = H + (size_t)e * TOKENS * HIDDEN;
    __shared__ __align__(16) bf16 As[2][128 * 32];
    __shared__ __align__(16) bf16 Bs[2][128 * 32];
    const int tid = threadIdx.x;
    f32x4 acc[4][4] = {};

    const int seg0 = tid, seg1 = tid + 256;
    const int r0 = seg0 >> 2, c0 = seg0 & 3;
    const int r1 = seg1 >> 2, c1 = seg1 & 3;
    const bf16* ga0 = A + (size_t)(brow + r0) * EMBED + c0 * 8;
    const bf16* ga1 = A + (size_t)(brow + r1) * EMBED + c1 * 8;
    const bf16* gb0 = Be + (size_t)(bcol + r0) * EMBED + c0 * 8;
    const bf16* gb1 = Be + (size_t)(bcol + r1) * EMBED + c1 * 8;

    const int lane = tid & 63, wid = tid >> 6;
    const int wv_r = (wid >> 1) * 64, wv_c = (wid & 1) * 64;
    const int fr = lane & 15, kb = (lane >> 4) * 8;

    auto STAGE = [&](int b, int kt) {
        gload_lds16(ga0 + kt, &As[b][seg0 * 8]);
        gload_lds16(ga1 + kt, &As[b][seg1 * 8]);
        gload_lds16(gb0 + kt, &Bs[b][seg0 * 8]);
        gload_lds16(gb1 + kt, &Bs[b][seg1 * 8]);
    };

    const int NT = EMBED / 32;
    STAGE(0, 0);
    __syncthreads();
    int cur = 0;
    for (int t = 0; t < NT; ++t) {
        if (t + 1 < NT) STAGE(cur ^ 1, (t + 1) * 32);
        bf16x8 af[4], bfr[4];
        #pragma unroll
        for (int m = 0; m < 4; m++) af[m] = *(const bf16x8*)&As[cur][(wv_r + m * 16 + fr) * 32 + kb];
        #pragma unroll
        for (int n = 0; n < 4; n++) bfr[n] = *(const bf16x8*)&Bs[cur][(wv_c + n * 16 + fr) * 32 + kb];
        #pragma unroll
        for (int m = 0; m < 4; m++)
            #pragma unroll
            for (int n = 0; n < 4; n++)
                acc[m][n] = __builtin_amdgcn_mfma_f32_16x16x32_bf16(af[m], bfr[n], acc[m][n], 0, 0, 0);
        __syncthreads();   // drains next-tile loads (vmcnt) + all reads of cur (lgkm)
        cur ^= 1;
    }

    #pragma unroll
    for (int n = 0; n < 4; n++) {
        const int col = bcol + wv_c + n * 16 + fr;
        const float bias = b1[e * HIDDEN + col];
        #pragma unroll
        for (int m = 0; m < 4; m++) {
            const int rowb = brow + wv_r + m * 16 + (lane >> 4) * 4;
            #pragma unroll
            for (int j = 0; j < 4; j++) {
                const int row = rowb + j;
                float v = acc[m][n][j] + bias;
                v = fmaxf(v, 0.f) * rw[(size_t)row * NEXP + e];
                He[(size_t)row * HIDDEN + col] = __float2bfloat16(v);
            }
        }
    }
}

// ---- GEMM pass 2 (2-phase dbuf): out = Sum_e h'_e @ W2_e (+ Sum_e w*b2), kc = expert ----
__global__ __launch_bounds__(256) void gemm2(const bf16* __restrict__ A,   // h' [NEXP][4096][HIDDEN]
                                             const bf16* __restrict__ Bt,  // w2t [NEXP][EMBED][HIDDEN]
                                             const float* __restrict__ b2, // [NEXP][EMBED]
                                             const float* __restrict__ rw, // [M][8]
                                             float* __restrict__ out) {    // [M][EMBED]
    const int e = blockIdx.z;         // expert = K-chunk
    const int brow = blockIdx.y * 128;
    const int bcol = blockIdx.x * 128;
    const bf16* Ae = A + (size_t)e * TOKENS * HIDDEN;
    const bf16* Be = Bt + (size_t)e * EMBED * HIDDEN;
    __shared__ __align__(16) bf16 As[2][128 * 32];
    __shared__ __align__(16) bf16 Bs[2][128 * 32];
    const int tid = threadIdx.x;
    f32x4 acc[4][4] = {};

    const int seg0 = tid, seg1 = tid + 256;
    const int r0 = seg0 >> 2, c0 = seg0 & 3;
    const int r1 = seg1 >> 2, c1 = seg1 & 3;
    const bf16* ga0 = Ae + (size_t)(brow + r0) * HIDDEN + c0 * 8;
    const bf16* ga1 = Ae + (size_t)(brow + r1) * HIDDEN + c1 * 8;
    const bf16* gb0 = Be + (size_t)(bcol + r0) * HIDDEN + c0 * 8;
    const bf16* gb1 = Be + (size_t)(bcol + r1) * HIDDEN + c1 * 8;

    const int lane = tid & 63, wid = tid >> 6;
    const int wv_r = (wid >> 1) * 64, wv_c = (wid & 1) * 64;
    const int fr = lane & 15, kb = (lane >> 4) * 8;

    auto STAGE = [&](int b, int kt) {
        gload_lds16(ga0 + kt, &As[b][seg0 * 8]);
        gload_lds16(ga1 + kt, &As[b][seg1 * 8]);
        gload_lds16(gb0 + kt, &Bs[b][seg0 * 8]);
        gload_lds16(gb1 + kt, &Bs[b][seg1 * 8]);
    };

    const int NT = HIDDEN / 32;   // 128 K-steps over this expert's K=4096
    STAGE(0, 0);
    __syncthreads();
    int cur = 0;
    for (int t = 0; t < NT; ++t) {
        if (t + 1 < NT) STAGE(cur ^ 1, (t + 1) * 32);
        bf16x8 af[4], bfr[4];
        #pragma unroll
        for (int m = 0; m < 4; m++) af[m] = *(const bf16x8*)&As[cur][(wv_r + m * 16 + fr) * 32 + kb];
        #pragma unroll
        for (int n = 0; n < 4; n++) bfr[n] = *(const bf16x8*)&Bs[cur][(wv_c + n * 16 + fr) * 32 + kb];
        #pragma unroll
        for (int m = 0; m < 4; m++)
            #pragma unroll
            for (int n = 0; n < 4; n++)
                acc[m][n] = __builtin_amdgcn_mfma_f32_16x16x32_bf16(af[m], bfr[n], acc[m][n], 0, 0, 0);
        __syncthreads();
        cur ^= 1;
    }

    #pragma unroll
    for (int n = 0; n < 4; n++) {
        const int col = bcol + wv_c + n * 16 + fr;
        #pragma unroll
        for (int m = 0; m < 4; m++) {
            const int rowb = brow + wv_r + m * 16 + (lane >> 4) * 4;
            #pragma unroll
            for (int j = 0; j < 4; j++) {
                const int row = rowb + j;
                float v = acc[m][n][j];
                if (e == 0) {
                    const float* wrow = rw + (size_t)row * NEXP;
                    float s = 0.f;
                    #pragma unroll
                    for (int ee = 0; ee < NEXP; ee++) s = fmaf(wrow[ee], b2[ee * EMBED + col], s);
                    v += s;
                }
                atomicAdd(out + (size_t)row * EMBED + col, v);
            }
        }
    }
}

extern "C" void kernel_launch(void* const* d_in, const int* in_sizes, int n_in,
                              void* d_out, int out_size, void* d_ws, size_t ws_size,
                              hipStream_t stream) {
    const float* x  = (const float*)d_in[0];
    const float* W1 = (const float*)d_in[1];
    const float* b1 = (const float*)d_in[2];
    const float* W2 = (const float*)d_in[3];
    const float* b2 = (const float*)d_in[4];
    const float* Wr = (const float*)d_in[5];
    const float* br = (const float*)d_in[6];
    float* out = (float*)d_out;

    uint8_t* ws = (uint8_t*)d_ws;
    size_t off = 0;
    auto walloc = [&](size_t bytes) -> void* {
        void* p = ws + off;
        off += (bytes + 255) & ~(size_t)255;
        return p;
    };
    float* rw  = (float*)walloc((size_t)TOKENS * NEXP * 4);
    bf16* xb   = (bf16*)walloc((size_t)TOKENS * EMBED * 2);
    bf16* w1t  = (bf16*)walloc((size_t)NEXP * HIDDEN * EMBED * 2);
    bf16* w2t  = (bf16*)walloc((size_t)NEXP * EMBED * HIDDEN * 2);
    bf16* hbuf = (bf16*)walloc((size_t)NEXP * TOKENS * HIDDEN * 2);  // 256 MB (ws >= 392 MB, proven R1)

    hipMemsetAsync(d_out, 0, (size_t)out_size * sizeof(float), stream);

    cvt_kernel<<<4096, 256, 0, stream>>>(x, xb, (size_t)TOKENS * EMBED);

    dim3 tb(32, 8);
    // W1 [e][d][h] -> w1t [e][h][d]
    transpose_cvt<<<dim3(HIDDEN / 32, EMBED / 32, NEXP), tb, 0, stream>>>(
        W1, w1t, EMBED, HIDDEN, (size_t)EMBED * HIDDEN, (size_t)HIDDEN * EMBED, EMBED);
    // W2 [e][h][n] -> w2t [e][n][h]
    transpose_cvt<<<dim3(EMBED / 32, HIDDEN / 32, NEXP), tb, 0, stream>>>(
        W2, w2t, HIDDEN, EMBED, (size_t)HIDDEN * EMBED, (size_t)EMBED * HIDDEN, HIDDEN);

    router_kernel<<<TOKENS, 64, 0, stream>>>(x, Wr, br, rw);

    gemm1<<<dim3(HIDDEN / 128, TOKENS / 128, NEXP), 256, 0, stream>>>(xb, w1t, b1, rw, hbuf);
    gemm2<<<dim3(EMBED / 128, TOKENS / 128, NEXP), 256, 0, stream>>>(hbuf, w2t, b2, rw, out);
}

// Round 5
// 946.181 us; speedup vs baseline: 1.3164x; 1.2146x over previous
//
#include <hip/hip_runtime.h>
#include <hip/hip_bf16.h>
#include <cstdint>
#include <cstddef>

#define EMBED  1024
#define NEXP   8
#define HIDDEN 4096
#define TOKENS 4096

typedef __attribute__((ext_vector_type(8))) short bf16x8;
typedef __attribute__((ext_vector_type(4))) float f32x4;
using bf16 = __hip_bfloat16;

// ---------------- async global->LDS (16B per lane) ----------------
__device__ __forceinline__ void gload_lds16(const void* g, void* l) {
    __builtin_amdgcn_global_load_lds((const __attribute__((address_space(1))) void*)g,
                                     (__attribute__((address_space(3))) void*)l,
                                     16, 0, 0);
}

// LDS byte swizzle: flip 16B-block index (bits 4-5) by row bits 1-2 (row = byte>>6).
// Involution; spreads the 16 rows of an MFMA fragment read across all 32 banks.
__device__ __forceinline__ int swz(int b) { return b ^ (((b >> 7) & 3) << 4); }

// ---------------- fp32 -> bf16 elementwise convert ----------------
__global__ void cvt_kernel(const float* __restrict__ in, bf16* __restrict__ out, size_t n) {
    size_t i = ((size_t)blockIdx.x * blockDim.x + threadIdx.x) * 4;
    if (i + 3 < n) {
        float4 v = *(const float4*)(in + i);
        out[i + 0] = __float2bfloat16(v.x);
        out[i + 1] = __float2bfloat16(v.y);
        out[i + 2] = __float2bfloat16(v.z);
        out[i + 3] = __float2bfloat16(v.w);
    }
}

// ------------- transpose + convert: out[e][n][k] = in[e][k][n] -------------
__global__ void transpose_cvt(const float* __restrict__ in, bf16* __restrict__ out,
                              int K, int N, size_t in_estride, size_t out_eoff, int ldo) {
    const int e = blockIdx.z;
    const float* ine = in + (size_t)e * in_estride;
    bf16* oute = out + (size_t)e * out_eoff;
    __shared__ float tile[32][33];
    const int n0 = blockIdx.x * 32, k0 = blockIdx.y * 32;
    const int tx = threadIdx.x, ty = threadIdx.y;
    #pragma unroll
    for (int i = ty; i < 32; i += 8)
        tile[i][tx] = ine[(size_t)(k0 + i) * N + n0 + tx];
    __syncthreads();
    #pragma unroll
    for (int i = ty; i < 32; i += 8)
        oute[(size_t)(n0 + i) * ldo + k0 + tx] = __float2bfloat16(tile[tx][i]);
}

// ---------------- router: per-token top-2 masked softmax ----------------
__global__ void router_kernel(const float* __restrict__ x, const float* __restrict__ Wr,
                              const float* __restrict__ br, float* __restrict__ w) {
    const int t = blockIdx.x;
    const int lane = threadIdx.x;  // 64 threads
    const float* xt = x + (size_t)t * EMBED;
    float s[NEXP];
    #pragma unroll
    for (int e = 0; e < NEXP; e++) s[e] = 0.f;
    for (int k = lane; k < EMBED; k += 64) {
        const float xv = xt[k];
        const float* wrk = Wr + (size_t)k * NEXP;
        #pragma unroll
        for (int e = 0; e < NEXP; e++) s[e] = fmaf(xv, wrk[e], s[e]);
    }
    #pragma unroll
    for (int e = 0; e < NEXP; e++) {
        #pragma unroll
        for (int off = 32; off >= 1; off >>= 1)
            s[e] += __shfl_xor(s[e], off);
    }
    if (lane == 0) {
        float sc[NEXP];
        #pragma unroll
        for (int e = 0; e < NEXP; e++) sc[e] = s[e] + br[e];
        int i1 = 0; float m1 = sc[0];
        #pragma unroll
        for (int e = 1; e < NEXP; e++) if (sc[e] > m1) { m1 = sc[e]; i1 = e; }
        int i2 = -1; float m2 = -1e30f;
        #pragma unroll
        for (int e = 0; e < NEXP; e++) if (e != i1 && sc[e] > m2) { m2 = sc[e]; i2 = e; }
        const float mx = fmaxf(m1, 0.f);
        const float denom = 6.f * expf(0.f - mx) + expf(m1 - mx) + expf(m2 - mx);
        #pragma unroll
        for (int e = 0; e < NEXP; e++) {
            float v = (e == i1) ? m1 : ((e == i2) ? m2 : 0.f);
            w[(size_t)t * NEXP + e] = expf(v - mx) / denom;
        }
    }
}

// ================== GEMM bodies: 3-slot ring, counted vmcnt, swizzled LDS ==================
// Tile 128x128, BK=32, 4 waves. LDS: 3 slots x (A 8KB + B 8KB) = 48KB -> 3 blocks/CU.

#define GEMM_PREAMBLE(Abase, Bbase, lda, ldb)                                            \
    __shared__ __align__(16) bf16 As[3][128 * 32];                                       \
    __shared__ __align__(16) bf16 Bs[3][128 * 32];                                       \
    const int tid = threadIdx.x;                                                         \
    f32x4 acc[4][4] = {};                                                                \
    int srow[2], scol[2];                                                                \
    _Pragma("unroll")                                                                    \
    for (int j = 0; j < 2; j++) {                                                        \
        int b0 = tid * 16 + j * 4096;                                                    \
        int bs = swz(b0);                                                                \
        srow[j] = bs >> 6; scol[j] = (bs & 63) >> 1;                                     \
    }                                                                                    \
    const bf16* ga0 = (Abase) + (size_t)(brow + srow[0]) * (lda) + scol[0];              \
    const bf16* ga1 = (Abase) + (size_t)(brow + srow[1]) * (lda) + scol[1];              \
    const bf16* gb0 = (Bbase) + (size_t)(bcol + srow[0]) * (ldb) + scol[0];              \
    const bf16* gb1 = (Bbase) + (size_t)(bcol + srow[1]) * (ldb) + scol[1];              \
    const int lane = tid & 63, wid = tid >> 6;                                           \
    const int wv_r = (wid >> 1) * 64, wv_c = (wid & 1) * 64;                             \
    const int fr = lane & 15, kbyte = (lane >> 4) * 16;                                  \
    int offA[4], offB[4];                                                                \
    _Pragma("unroll")                                                                    \
    for (int m = 0; m < 4; m++) {                                                        \
        offA[m] = swz((wv_r + m * 16 + fr) * 64 + kbyte);                                \
        offB[m] = swz((wv_c + m * 16 + fr) * 64 + kbyte);                                \
    }

#define STAGE(s, kt)                                                                     \
    do {                                                                                 \
        gload_lds16(ga0 + (kt), &As[s][tid * 8]);                                        \
        gload_lds16(ga1 + (kt), &As[s][tid * 8 + 2048]);                                 \
        gload_lds16(gb0 + (kt), &Bs[s][tid * 8]);                                        \
        gload_lds16(gb1 + (kt), &Bs[s][tid * 8 + 2048]);                                 \
    } while (0)

#define GEMM_KLOOP(NT)                                                                   \
    STAGE(0, 0);                                                                         \
    STAGE(1, 32);                                                                        \
    {                                                                                    \
        int slot = 0, nslot = 2;                                                         \
        for (int t = 0; t < (NT); ++t) {                                                 \
            if (t + 2 < (NT)) { STAGE(nslot, (t + 2) * 32); }                            \
            if (t < (NT) - 2)       asm volatile("s_waitcnt vmcnt(8)" ::: "memory");     \
            else if (t == (NT) - 2) asm volatile("s_waitcnt vmcnt(4)" ::: "memory");     \
            else                    asm volatile("s_waitcnt vmcnt(0)" ::: "memory");     \
            __builtin_amdgcn_s_barrier();                                                \
            __builtin_amdgcn_sched_barrier(0);                                           \
            const char* Ab = (const char*)As[slot];                                      \
            const char* Bb = (const char*)Bs[slot];                                      \
            bf16x8 af[4], bfr[4];                                                        \
            _Pragma("unroll")                                                            \
            for (int m = 0; m < 4; m++) af[m] = *(const bf16x8*)(Ab + offA[m]);          \
            _Pragma("unroll")                                                            \
            for (int n = 0; n < 4; n++) bfr[n] = *(const bf16x8*)(Bb + offB[n]);         \
            __builtin_amdgcn_s_setprio(1);                                               \
            _Pragma("unroll")                                                            \
            for (int m = 0; m < 4; m++)                                                  \
                _Pragma("unroll")                                                        \
                for (int n = 0; n < 4; n++)                                              \
                    acc[m][n] = __builtin_amdgcn_mfma_f32_16x16x32_bf16(af[m], bfr[n],   \
                                                                       acc[m][n], 0, 0, 0); \
            __builtin_amdgcn_s_setprio(0);                                               \
            asm volatile("" ::: "memory");                                               \
            __builtin_amdgcn_s_barrier();                                                \
            slot = (slot == 2) ? 0 : slot + 1;                                           \
            nslot = (nslot == 2) ? 0 : nslot + 1;                                        \
        }                                                                                \
    }

// ---- GEMM pass 1: h'[e][row][col] = w[t,e] * relu(x @ W1_e + b1_e) ----
__global__ __launch_bounds__(256, 3) void gemm1(const bf16* __restrict__ A,   // x [4096][EMBED]
                                                const bf16* __restrict__ Bt,  // w1t [e][HIDDEN][EMBED]
                                                const float* __restrict__ b1,
                                                const float* __restrict__ rw,
                                                bf16* __restrict__ H) {
    const int e = blockIdx.z;
    const int brow = blockIdx.y * 128;
    const int bcol = blockIdx.x * 128;
    const bf16* Be = Bt + (size_t)e * HIDDEN * EMBED;
    bf16* He = H + (size_t)e * TOKENS * HIDDEN;

    GEMM_PREAMBLE(A, Be, EMBED, EMBED)
    GEMM_KLOOP(EMBED / 32)

    #pragma unroll
    for (int n = 0; n < 4; n++) {
        const int col = bcol + wv_c + n * 16 + fr;
        const float bias = b1[e * HIDDEN + col];
        #pragma unroll
        for (int m = 0; m < 4; m++) {
            const int rowb = brow + wv_r + m * 16 + (lane >> 4) * 4;
            #pragma unroll
            for (int j = 0; j < 4; j++) {
                const int row = rowb + j;
                float v = acc[m][n][j] + bias;
                v = fmaxf(v, 0.f) * rw[(size_t)row * NEXP + e];
                He[(size_t)row * HIDDEN + col] = __float2bfloat16(v);
            }
        }
    }
}

// ---- GEMM pass 2: out = Sum_e h'_e @ W2_e (+ Sum_e w*b2), z = expert ----
__global__ __launch_bounds__(256, 3) void gemm2(const bf16* __restrict__ A,   // h' [NEXP][4096][HIDDEN]
                                                const bf16* __restrict__ Bt,  // w2t [NEXP][EMBED][HIDDEN]
                                                const float* __restrict__ b2, // [NEXP][EMBED]
                                                const float* __restrict__ rw, // [M][8]
                                                float* __restrict__ out) {    // [M][EMBED]
    const int e = blockIdx.z;
    const int brow = blockIdx.y * 128;
    const int bcol = blockIdx.x * 128;
    const bf16* Ae = A + (size_t)e * TOKENS * HIDDEN;
    const bf16* Be = Bt + (size_t)e * EMBED * HIDDEN;

    GEMM_PREAMBLE(Ae, Be, HIDDEN, HIDDEN)
    GEMM_KLOOP(HIDDEN / 32)

    #pragma unroll
    for (int n = 0; n < 4; n++) {
        const int col = bcol + wv_c + n * 16 + fr;
        #pragma unroll
        for (int m = 0; m < 4; m++) {
            const int rowb = brow + wv_r + m * 16 + (lane >> 4) * 4;
            #pragma unroll
            for (int j = 0; j < 4; j++) {
                const int row = rowb + j;
                float v = acc[m][n][j];
                if (e == 0) {
                    const float* wrow = rw + (size_t)row * NEXP;
                    float s = 0.f;
                    #pragma unroll
                    for (int ee = 0; ee < NEXP; ee++) s = fmaf(wrow[ee], b2[ee * EMBED + col], s);
                    v += s;
                }
                atomicAdd(out + (size_t)row * EMBED + col, v);
            }
        }
    }
}

extern "C" void kernel_launch(void* const* d_in, const int* in_sizes, int n_in,
                              void* d_out, int out_size, void* d_ws, size_t ws_size,
                              hipStream_t stream) {
    const float* x  = (const float*)d_in[0];
    const float* W1 = (const float*)d_in[1];
    const float* b1 = (const float*)d_in[2];
    const float* W2 = (const float*)d_in[3];
    const float* b2 = (const float*)d_in[4];
    const float* Wr = (const float*)d_in[5];
    const float* br = (const float*)d_in[6];
    float* out = (float*)d_out;

    uint8_t* ws = (uint8_t*)d_ws;
    size_t off = 0;
    auto walloc = [&](size_t bytes) -> void* {
        void* p = ws + off;
        off += (bytes + 255) & ~(size_t)255;
        return p;
    };
    float* rw  = (float*)walloc((size_t)TOKENS * NEXP * 4);
    bf16* xb   = (bf16*)walloc((size_t)TOKENS * EMBED * 2);
    bf16* w1t  = (bf16*)walloc((size_t)NEXP * HIDDEN * EMBED * 2);
    bf16* w2t  = (bf16*)walloc((size_t)NEXP * EMBED * HIDDEN * 2);
    bf16* hbuf = (bf16*)walloc((size_t)NEXP * TOKENS * HIDDEN * 2);  // 256 MB

    hipMemsetAsync(d_out, 0, (size_t)out_size * sizeof(float), stream);

    cvt_kernel<<<4096, 256, 0, stream>>>(x, xb, (size_t)TOKENS * EMBED);

    dim3 tb(32, 8);
    // W1 [e][d][h] -> w1t [e][h][d]
    transpose_cvt<<<dim3(HIDDEN / 32, EMBED / 32, NEXP), tb, 0, stream>>>(
        W1, w1t, EMBED, HIDDEN, (size_t)EMBED * HIDDEN, (size_t)HIDDEN * EMBED, EMBED);
    // W2 [e][h][n] -> w2t [e][n][h]
    transpose_cvt<<<dim3(EMBED / 32, HIDDEN / 32, NEXP), tb, 0, stream>>>(
        W2, w2t, HIDDEN, EMBED, (size_t)HIDDEN * EMBED, (size_t)EMBED * HIDDEN, HIDDEN);

    router_kernel<<<TOKENS, 64, 0, stream>>>(x, Wr, br, rw);

    gemm1<<<dim3(HIDDEN / 128, TOKENS / 128, NEXP), 256, 0, stream>>>(xb, w1t, b1, rw, hbuf);
    gemm2<<<dim3(EMBED / 128, TOKENS / 128, NEXP), 256, 0, stream>>>(hbuf, w2t, b2, rw, out);
}